// Round 12
// baseline (221.692 us; speedup 1.0000x reference)
//
#include <hip/hip_runtime.h>
#include <stdint.h>

#define S_LEN 2048
#define NH 16
#define DM 1024
#define HD 64
#define NB 2
#define TOK (NB * S_LEN)  // 4096

typedef __attribute__((ext_vector_type(8))) short short8v;  // 8 bf16 = 4 VGPR
typedef __attribute__((ext_vector_type(4))) float f32x4;
typedef __attribute__((ext_vector_type(2))) unsigned int u32x2;
typedef unsigned short u16;
typedef unsigned int u32;

__device__ __forceinline__ float bf2f(u16 u) {
    u32 x = ((u32)u) << 16;
    return __builtin_bit_cast(float, x);
}
__device__ __forceinline__ u16 f2bf(float f) {  // RNE
    u32 u = __builtin_bit_cast(u32, f);
    return (u16)((u + 0x7FFFu + ((u >> 16) & 1u)) >> 16);
}
// pack 2 floats -> 2 bf16 in one instr (RNE); lo -> bits 15:0
__device__ __forceinline__ u32 cvtpk(float lo, float hi) {
    u32 r;
    asm("v_cvt_pk_bf16_f32 %0, %1, %2" : "=v"(r) : "v"(lo), "v"(hi));
    return r;
}

// async global->LDS, 16B per lane. LDS dest = wave-uniform base + lane*16 (HW).
__device__ __forceinline__ void gld_lds16(const void* g, void* lds_base_uniform) {
    auto gp = (const __attribute__((address_space(1))) u32*)(uintptr_t)g;
    auto lp = (__attribute__((address_space(3))) u32*)(uintptr_t)(u32)(uintptr_t)lds_base_uniform;
    __builtin_amdgcn_global_load_lds(gp, lp, 16, 0, 0);
}

// ---------------------------------------------------------------------------
// dtype sniffer: flag=1 if x is bf16, 0 if fp32.
// ---------------------------------------------------------------------------
__global__ void detect_dtype(const u32* __restrict__ xw, int* __restrict__ flag) {
    __shared__ int cnt[4];
    const int t = threadIdx.x;
    int c = 0;
#pragma unroll
    for (int j = 0; j < 16; ++j) {
        const u32 wd = xw[(t * 16 + j) * 64];
        const u32 e = (wd >> 7) & 0xFF;
        c += (e >= 0x58 && e <= 0x98) ? 1 : 0;
    }
#pragma unroll
    for (int off = 1; off < 64; off <<= 1) c += __shfl_xor(c, off);
    if ((t & 63) == 0) cnt[t >> 6] = c;
    __syncthreads();
    if (t == 0) flag[0] = (cnt[0] + cnt[1] + cnt[2] + cnt[3] >= 2600) ? 1 : 0;
}

// ---------------------------------------------------------------------------
// Fused fp32 -> bf16 conversion of x, w_qkv, w_out (copy-through when bf16)
// + RoPE table, PAIR-MAJOR layout for coalesced epilogue loads:
//   tabp[i2][s] = {cos(s*f(2*i2)), sin(s*f(2*i2)),
//                  cos(s*f(2*i2+1)), sin(s*f(2*i2+1))},  f(i)=10000^(-2i/64)
// i2 = d0/4 in [0,16). 16B/entry; lanes read consecutive s -> contiguous.
// ---------------------------------------------------------------------------
#define XCH (TOK * DM / 8)           // 524288
#define WQCH (3 * DM * DM / 8)       // 393216
#define WOCH (DM * DM / 8)           // 131072
#define CONVTOT (XCH + WQCH + WOCH)  // 1048576
#define TABN (S_LEN * 16)            // 32768 entries x 16B = 512 KB
__global__ __launch_bounds__(256) void convert_all(
    const void* __restrict__ xs, const void* __restrict__ wqs, const void* __restrict__ wos,
    u16* __restrict__ xd, u16* __restrict__ wqd, u16* __restrict__ wod,
    float* __restrict__ tab, const int* __restrict__ flagp) {
    int i = blockIdx.x * 256 + threadIdx.x;
    if (i >= CONVTOT) {  // table region
        const int e = i - CONVTOT;  // 0..32767
        const int s = e & 2047;
        const int i2 = e >> 11;  // 0..15
        const float fa = expf(-(float)(2 * i2) * 0.2878231366242557f);
        const float fb = expf(-(float)(2 * i2 + 1) * 0.2878231366242557f);
        float sa, ca, sb, cb;
        sincosf((float)s * fa, &sa, &ca);
        sincosf((float)s * fb, &sb, &cb);
        f32x4 tv = {ca, sa, cb, sb};
        *(f32x4*)(tab + (size_t)e * 4) = tv;
        return;
    }
    const void* src;
    u16* dst;
    if (i < XCH) {
        src = xs; dst = xd;
    } else if (i < XCH + WQCH) {
        src = wqs; dst = wqd; i -= XCH;
    } else {
        src = wos; dst = wod; i -= XCH + WQCH;
    }
    if (flagp[0]) {
        ((short8v*)dst)[i] = ((const short8v*)src)[i];
    } else {
        const f32x4 v0 = ((const f32x4*)src)[2 * i];
        const f32x4 v1 = ((const f32x4*)src)[2 * i + 1];
        short8v o;
#pragma unroll
        for (int q = 0; q < 4; ++q) o[q] = (short)f2bf(v0[q]);
#pragma unroll
        for (int q = 0; q < 4; ++q) o[4 + q] = (short)f2bf(v1[q]);
        ((short8v*)dst)[i] = o;
    }
}

// ---------------------------------------------------------------------------
// GEMM C[m,n] = sum_k A[m,k]*Bt[n,k] + bias[n]; bf16 in, fp32 accum.
// 128x128 tile, BK=32, 3-buffer counted-vmcnt pipeline (R7-verified).
// Compile-time MODE:
//   MODE 0: standard epilogue -> Cv (lane holds 4 consecutive n; 8B/16B
//           vector stores).
//   MODE 1 (q/k, grid.x=16): RoPE fused. Lane's 4 consecutive n = 2 rotation
//           pairs; coalesced pair-major table load; 8B stores into qws/kws
//           (B,H,S,64).
//   MODE 2 (v, grid.x=8, bn+=2048): MFMA operands flipped so lane holds 4
//           consecutive tokens at fixed d; 8B stores direct into vT (B,H,64,S).
// ---------------------------------------------------------------------------
template <int MODE>
__global__ __launch_bounds__(256) void gemm_k(
    const u16* __restrict__ A, const u16* __restrict__ Bt,
    const void* __restrict__ biasv, void* __restrict__ Cv,
    int M, int N, int K, const int* __restrict__ flagp, int out_flagged,
    u16* __restrict__ qws, u16* __restrict__ kws,
    u16* __restrict__ vT, const float* __restrict__ tab) {
    __shared__ __align__(16) u16 lA[3][128 * 32];
    __shared__ __align__(16) u16 lB[3][128 * 32];
    const int fl = flagp[0];
    const int fo = out_flagged ? fl : 1;  // MODE 0: 1 => bf16 output

    const int tid = threadIdx.x;
    const int w = __builtin_amdgcn_readfirstlane(tid >> 6);
    const int lane = tid & 63;
    const int quad = lane >> 4;
    const int l16 = lane & 15;
    const int bm = blockIdx.y * 128;
    const int bn = (MODE == 2 ? 2048 : 0) + blockIdx.x * 128;
    const int wm = (w >> 1) * 64;
    const int wn = (w & 1) * 64;

    f32x4 acc[4][4];
#pragma unroll
    for (int i = 0; i < 4; ++i)
#pragma unroll
        for (int j = 0; j < 4; ++j) acc[i][j] = {0.f, 0.f, 0.f, 0.f};

    const int kiters = K >> 5;
#define GEMM_STAGE(kk, buf)                                                            \
    {                                                                                  \
        _Pragma("unroll") for (int c = 0; c < 2; ++c) {                                \
            const int chunk = w * 2 + c;                                               \
            const int off = chunk * 1024 + lane * 16;                                  \
            const int m_ = off >> 6;                                                   \
            const int kb_ = off & 63;                                                  \
            gld_lds16((const char*)(A + (size_t)(bm + m_) * K + (kk) * 32) + kb_,      \
                      (char*)&lA[buf][0] + chunk * 1024);                              \
            gld_lds16((const char*)(Bt + (size_t)(bn + m_) * K + (kk) * 32) + kb_,     \
                      (char*)&lB[buf][0] + chunk * 1024);                              \
        }                                                                              \
    }

    GEMM_STAGE(0, 0);
    if (kiters > 1) GEMM_STAGE(1, 1);
    int cur = 0;
    for (int kk = 0; kk < kiters; ++kk) {
        if (kk + 1 < kiters) {
            asm volatile("s_waitcnt vmcnt(4)" ::: "memory");
        } else {
            asm volatile("s_waitcnt vmcnt(0)" ::: "memory");
        }
        __builtin_amdgcn_s_barrier();
        if (kk + 2 < kiters) {
            const int nb = (cur + 2 >= 3) ? cur - 1 : cur + 2;
            GEMM_STAGE(kk + 2, nb);
        }

        short8v af[4], bf[4];
#pragma unroll
        for (int t = 0; t < 4; ++t) {
            af[t] = *(const short8v*)&lA[cur][(wm + t * 16 + l16) * 32 + quad * 8];
            bf[t] = *(const short8v*)&lB[cur][(wn + t * 16 + l16) * 32 + quad * 8];
        }
        __builtin_amdgcn_s_setprio(1);
        if constexpr (MODE == 2) {  // rows <- m: lane holds 4 consecutive tokens
#pragma unroll
            for (int i = 0; i < 4; ++i)
#pragma unroll
                for (int j = 0; j < 4; ++j)
                    acc[i][j] =
                        __builtin_amdgcn_mfma_f32_16x16x32_bf16(af[i], bf[j], acc[i][j], 0, 0, 0);
        } else {  // rows <- n: lane holds 4 consecutive n
#pragma unroll
            for (int i = 0; i < 4; ++i)
#pragma unroll
                for (int j = 0; j < 4; ++j)
                    acc[i][j] =
                        __builtin_amdgcn_mfma_f32_16x16x32_bf16(bf[j], af[i], acc[i][j], 0, 0, 0);
        }
        __builtin_amdgcn_s_setprio(0);
        cur = (cur == 2) ? 0 : cur + 1;
    }
#undef GEMM_STAGE

    if constexpr (MODE == 0) {
        // acc[i][j] = C[m=bm+wm+i*16+l16][n=bn+wn+j*16+quad*4+r]
#pragma unroll
        for (int j = 0; j < 4; ++j) {
            const int n0 = bn + wn + j * 16 + quad * 4;
            float bv0, bv1, bv2, bv3;
            if (fl) {
                const u32x2 bw = *(const u32x2*)((const u16*)biasv + n0);
                bv0 = bf2f((u16)(bw.x & 0xffff));
                bv1 = bf2f((u16)(bw.x >> 16));
                bv2 = bf2f((u16)(bw.y & 0xffff));
                bv3 = bf2f((u16)(bw.y >> 16));
            } else {
                const f32x4 bw = *(const f32x4*)((const float*)biasv + n0);
                bv0 = bw[0]; bv1 = bw[1]; bv2 = bw[2]; bv3 = bw[3];
            }
#pragma unroll
            for (int i = 0; i < 4; ++i) {
                const size_t base = (size_t)(bm + wm + i * 16 + l16) * N + n0;
                const float v0 = acc[i][j][0] + bv0, v1 = acc[i][j][1] + bv1;
                const float v2 = acc[i][j][2] + bv2, v3 = acc[i][j][3] + bv3;
                if (fo) {
                    u32x2 ov;
                    ov.x = cvtpk(v0, v1);
                    ov.y = cvtpk(v2, v3);
                    *(u32x2*)((u16*)Cv + base) = ov;
                } else {
                    f32x4 ov = {v0, v1, v2, v3};
                    *(f32x4*)((float*)Cv + base) = ov;
                }
            }
        }
    } else if constexpr (MODE == 2) {
        // acc[i][j] = C[m=bm+wm+i*16+quad*4+r][n=bn+wn+j*16+l16]
        // 4 consecutive tokens at fixed d -> 8B stores into vT (B,H,64,S)
#pragma unroll
        for (int j = 0; j < 4; ++j) {
            const int n = bn + wn + j * 16 + l16;
            const float bv = fl ? bf2f(((const u16*)biasv)[n]) : ((const float*)biasv)[n];
            const int vcol = n - 2048;
            const int hh = vcol >> 6, d = vcol & 63;
#pragma unroll
            for (int i = 0; i < 4; ++i) {
                const int m0 = bm + wm + i * 16 + quad * 4;
                const int bb = m0 >> 11, s0 = m0 & 2047;
                u32x2 ov;
                ov.x = cvtpk(acc[i][j][0] + bv, acc[i][j][1] + bv);
                ov.y = cvtpk(acc[i][j][2] + bv, acc[i][j][3] + bv);
                *(u32x2*)(vT + ((size_t)((bb * NH + hh) * HD + d)) * S_LEN + s0) = ov;
            }
        }
    } else {
        // q/k: acc[i][j] = C[m=bm+wm+i*16+l16][n=bn+wn+j*16+quad*4+r]
        // 4 consecutive n = 2 RoPE pairs; pair-major coalesced table load
        const bool isq = (blockIdx.x < 8);
        u16* outp = isq ? qws : kws;
#pragma unroll
        for (int j = 0; j < 4; ++j) {
            const int n0 = bn + wn + j * 16 + quad * 4;
            float bv0, bv1, bv2, bv3;
            if (fl) {
                const u32x2 bw = *(const u32x2*)((const u16*)biasv + n0);
                bv0 = bf2f((u16)(bw.x & 0xffff));
                bv1 = bf2f((u16)(bw.x >> 16));
                bv2 = bf2f((u16)(bw.y & 0xffff));
                bv3 = bf2f((u16)(bw.y >> 16));
            } else {
                const f32x4 bw = *(const f32x4*)((const float*)biasv + n0);
                bv0 = bw[0]; bv1 = bw[1]; bv2 = bw[2]; bv3 = bw[3];
            }
            const int nc = n0 & 1023;  // strip q/k bit
            const int hh = nc >> 6;    // head
            const int d0 = nc & 63;    // 4-aligned dim offset
            const int i2u = d0 >> 2;   // pair-major table row
#pragma unroll
            for (int i = 0; i < 4; ++i) {
                const int m = bm + wm + i * 16 + l16;
                const int bb = m >> 11, s = m & 2047;
                // lanes have consecutive s -> 16B x 16 lanes contiguous
                const f32x4 cs4 = *(const f32x4*)(tab + ((size_t)i2u * S_LEN + s) * 4);
                const float v0 = acc[i][j][0] + bv0, v1 = acc[i][j][1] + bv1;
                const float v2 = acc[i][j][2] + bv2, v3 = acc[i][j][3] + bv3;
                const float o0 = v0 * cs4[0] - v1 * cs4[1];
                const float o1 = v0 * cs4[1] + v1 * cs4[0];
                const float o2 = v2 * cs4[2] - v3 * cs4[3];
                const float o3 = v2 * cs4[3] + v3 * cs4[2];
                u32x2 ov;
                ov.x = cvtpk(o0, o1);
                ov.y = cvtpk(o2, o3);
                *(u32x2*)(outp + ((size_t)((bb * NH + hh) * S_LEN + s)) * HD + d0) = ov;
            }
        }
    }
}

// ---------------------------------------------------------------------------
// Flash attention, 2-halves-per-wave (work-efficiency). 256-thread blocks =
// 4 waves; each wave owns 32 q-rows as halves at +0/+64 within a 128-row
// block. Grid 512: id = qbr*32 + g, g=(b,h) low 5 bits -> XCD pin;
// qb = qbr<8 ? 15-qbr : qbr-8 so co-resident blocks id and id+256 have trip
// counts summing to a constant 34 (makespan balance).
//
// BOTH halves share each K/V tile: per-iteration staging, waits, barrier,
// and K-fragment LDS reads are unchanged but feed 2x the MFMA work.
// Block-iterations drop 16896 -> 8704 vs R10.
// K,V 2-buffered; issue-after-barrier; vmcnt(0) at top (loads get a full
// iteration to land - R6-proven safety structure). Halves serialized
// (sm0->PV0->sm1->PV1) through separate P buffers; per-half state in
// statically-named registers (token-pasted macro, no runtime indexing).
// Causal: half0 skips the last tile; diag at kt==2qb (h0) / 2qb+1 (h1);
// mask condition is panel-local and identical for both halves.
// LDS = 16K(Kx2) + 16K(Vx2) + 18K(P) = 50KB -> 3 blocks/CU.
// ---------------------------------------------------------------------------
__global__ __launch_bounds__(256, 3) void attn_kernel(
    const u16* __restrict__ qws, const u16* __restrict__ kws,
    const u16* __restrict__ vT, u16* __restrict__ ows) {
    __shared__ __align__(16) u16 kl[2][64 * 64];       // K 2-buf, 16 KB
    __shared__ __align__(16) u16 vl[2][64 * 64];       // V 2-buf, 16 KB
    __shared__ __align__(16) u32 pl32[4][2][16 * 36];  // per-wave,per-half P, 18 KB
    const int t = threadIdx.x;
    const int w = __builtin_amdgcn_readfirstlane(t >> 6);
    const int lane = t & 63;
    const int quad = lane >> 4;
    const int l16 = lane & 15;

    const int id = blockIdx.x;
    const int g = id & 31;  // (b,h) -> XCD pin g%8
    const int qbr = id >> 5;
    const int qb = (qbr < 8) ? (15 - qbr) : (qbr - 8);  // paired makespan
    const int h = g & 15, b = g >> 4;
    const int qrow = qb * 128 + w * 16;  // half0 rows; half1 = +64
    const int ktl0 = 2 * qb;             // last tile for half 0 (diag)
    const int ktl1 = 2 * qb + 1;         // last tile for half 1 (diag)

    const size_t bh = (size_t)(b * NH + h);
    const u16* qbp = qws + bh * (size_t)S_LEN * HD;
    const u16* kb = kws + bh * (size_t)S_LEN * HD;
    const u16* vb = vT + bh * (size_t)HD * S_LEN;

    // staging geometry: wave w stages rows [w*8+s*32 .. +7], lane -> 16B
    const int r0 = lane >> 3;          // row within 8-row group
    const int srcc = (lane & 7) ^ r0;  // pre-swizzled col16
    const int xorb = (l16 & 7) << 4;   // read-side swizzle XOR

    short8v qf0[2], qf1[2];
#pragma unroll
    for (int hf = 0; hf < 2; ++hf) {
        qf0[hf] = *(const short8v*)(qbp + (size_t)(qrow + l16) * HD + hf * 32 + quad * 8);
        qf1[hf] = *(const short8v*)(qbp + (size_t)(qrow + 64 + l16) * HD + hf * 32 + quad * 8);
    }

    f32x4 oacc0[4], oacc1[4];  // row = d (quad*4+r), col = q (l16)
#pragma unroll
    for (int d = 0; d < 4; ++d) {
        oacc0[d] = {0.f, 0.f, 0.f, 0.f};
        oacc1[d] = {0.f, 0.f, 0.f, 0.f};
    }
    float mrow0 = -__builtin_inff(), mrow1 = -__builtin_inff();
    float lrow0 = 0.f, lrow1 = 0.f;

#define STAGE_K(kt, buf)                                                            \
    {                                                                               \
        _Pragma("unroll") for (int s = 0; s < 2; ++s) {                             \
            const int row = w * 8 + s * 32 + r0;                                    \
            gld_lds16(kb + (size_t)((kt) * 64 + row) * HD + srcc * 8,               \
                      (char*)&kl[buf][0] + w * 1024 + s * 4096);                    \
        }                                                                           \
    }
#define STAGE_V(kt, buf)                                                            \
    {                                                                               \
        _Pragma("unroll") for (int s = 0; s < 2; ++s) {                             \
            const int row = w * 8 + s * 32 + r0;                                    \
            gld_lds16(vb + (size_t)row * S_LEN + (kt) * 64 + srcc * 8,              \
                      (char*)&vl[buf][0] + w * 1024 + s * 4096);                    \
        }                                                                           \
    }

// softmax + PV for one half (hh = literal 0/1 token; S = f32x4[4] scores)
#define SMPV(hh, S, DIAG)                                                              \
    {                                                                                  \
        float sv[16];                                                                  \
        _Pragma("unroll") for (int sub = 0; sub < 4; ++sub)                            \
            _Pragma("unroll") for (int r = 0; r < 4; ++r)                              \
                sv[sub * 4 + r] = S[sub][r] * 0.125f;                                  \
        if (DIAG) {                                                                    \
            const int qloc = w * 16 + l16;                                             \
            _Pragma("unroll") for (int sub = 0; sub < 4; ++sub)                        \
                _Pragma("unroll") for (int r = 0; r < 4; ++r)                          \
                    if (sub * 16 + quad * 4 + r > qloc)                                \
                        sv[sub * 4 + r] = -__builtin_inff();                           \
        }                                                                              \
        float a0 = fmaxf(sv[0], sv[1]), a1 = fmaxf(sv[2], sv[3]);                      \
        float a2 = fmaxf(sv[4], sv[5]), a3 = fmaxf(sv[6], sv[7]);                      \
        float a4 = fmaxf(sv[8], sv[9]), a5 = fmaxf(sv[10], sv[11]);                    \
        float a6 = fmaxf(sv[12], sv[13]), a7 = fmaxf(sv[14], sv[15]);                  \
        a0 = fmaxf(a0, a1); a2 = fmaxf(a2, a3);                                        \
        a4 = fmaxf(a4, a5); a6 = fmaxf(a6, a7);                                        \
        a0 = fmaxf(a0, a2); a4 = fmaxf(a4, a6);                                        \
        float mx = fmaxf(a0, a4);                                                      \
        mx = fmaxf(mx, __shfl_xor(mx, 16));                                            \
        mx = fmaxf(mx, __shfl_xor(mx, 32));                                            \
        const float mnew = fmaxf(mrow##hh, mx);                                        \
        const float alpha = __expf(mrow##hh - mnew);                                   \
        mrow##hh = mnew;                                                               \
        float p[16];                                                                   \
        _Pragma("unroll") for (int i = 0; i < 16; ++i) p[i] = __expf(sv[i] - mnew);    \
        float c0 = p[0] + p[1], c1 = p[2] + p[3], c2_ = p[4] + p[5], c3 = p[6] + p[7]; \
        float c4 = p[8] + p[9], c5 = p[10] + p[11], c6 = p[12] + p[13],                \
              c7 = p[14] + p[15];                                                      \
        c0 += c1; c2_ += c3; c4 += c5; c6 += c7;                                       \
        c0 += c2_; c4 += c6;                                                           \
        float ps = c0 + c4;                                                            \
        ps += __shfl_xor(ps, 16);                                                      \
        ps += __shfl_xor(ps, 32);                                                      \
        lrow##hh = lrow##hh * alpha + ps;                                              \
        _Pragma("unroll") for (int d = 0; d < 4; ++d) oacc##hh[d] *= alpha;            \
        u32* prow = &pl32[w][hh][l16 * 36];                                            \
        _Pragma("unroll") for (int sub = 0; sub < 4; ++sub) {                          \
            u32x2 pw;                                                                  \
            pw.x = cvtpk(p[sub * 4 + 0], p[sub * 4 + 1]);                              \
            pw.y = cvtpk(p[sub * 4 + 2], p[sub * 4 + 3]);                              \
            *(u32x2*)&prow[sub * 8 + quad * 2] = pw;                                   \
        }                                                                              \
        asm volatile("s_waitcnt lgkmcnt(0)" ::: "memory");                             \
        __builtin_amdgcn_sched_barrier(0);                                             \
        __builtin_amdgcn_s_setprio(1);                                                 \
        _Pragma("unroll") for (int c2 = 0; c2 < 2; ++c2) {                             \
            const short8v pf =                                                         \
                *(const short8v*)&pl32[w][hh][l16 * 36 + c2 * 16 + quad * 4];          \
            _Pragma("unroll") for (int d = 0; d < 4; ++d) {                            \
                const int lin = (d * 16 + l16) * 128 + c2 * 64 + quad * 16;            \
                const short8v vfd = *(const short8v*)(Vb + (lin ^ xorb));              \
                oacc##hh[d] =                                                          \
                    __builtin_amdgcn_mfma_f32_16x16x32_bf16(vfd, pf, oacc##hh[d], 0, 0, 0); \
            }                                                                          \
        }                                                                              \
        __builtin_amdgcn_s_setprio(0);                                                 \
    }

    // prologue: K[0] -> kl[0], V[0] -> vl[0]
    STAGE_K(0, 0);
    STAGE_V(0, 0);

    for (int kt = 0; kt <= ktl1; ++kt) {
        asm volatile("s_waitcnt vmcnt(0)" ::: "memory");  // K[kt],V[kt] landed
        __builtin_amdgcn_s_barrier();                     // all waves' tiles visible
        asm volatile("" ::: "memory");
        if (kt < ktl1) {  // prefetch next tile (full iteration to land)
            STAGE_V(kt + 1, (kt + 1) & 1);
            STAGE_K(kt + 1, (kt + 1) & 1);
        }
        const char* Kb = (const char*)&kl[kt & 1][0];
        const char* Vb = (const char*)&vl[kt & 1][0];

        // QK for both halves, sharing the K-fragment LDS reads
        const bool h0act = (kt <= ktl0);
        f32x4 sA[4], sB[4];
        __builtin_amdgcn_s_setprio(1);
#pragma unroll
        for (int sub = 0; sub < 4; ++sub) {
            const int lin = (sub * 16 + l16) * 128 + quad * 16;
            const short8v k0 = *(const short8v*)(Kb + (lin ^ xorb));
            const short8v k1 = *(const short8v*)(Kb + ((lin + 64) ^ xorb));
            f32x4 a = {0.f, 0.f, 0.f, 0.f};
            if (h0act) {
                a = __builtin_amdgcn_mfma_f32_16x16x32_bf16(k0, qf0[0], a, 0, 0, 0);
                a = __builtin_amdgcn_mfma_f32_16x16x32_bf16(k1, qf0[1], a, 0, 0, 0);
            }
            sA[sub] = a;
            f32x4 bq = {0.f, 0.f, 0.f, 0.f};
            bq = __builtin_amdgcn_mfma_f32_16x16x32_bf16(k0, qf1[0], bq, 0, 0, 0);
            bq = __builtin_amdgcn_mfma_f32_16x16x32_bf16(k1, qf1[1], bq, 0, 0, 0);
            sB[sub] = bq;
        }
        __builtin_amdgcn_s_setprio(0);

        if (h0act) SMPV(0, sA, kt == ktl0);
        SMPV(1, sB, kt == ktl1);
    }
#undef STAGE_K
#undef STAGE_V
#undef SMPV

    // epilogue: O[q][d], q = qrow + hh*64 + l16, d = df*16+quad*4+r
    {
        const float inv = 1.0f / lrow0;
        const size_t rowbase = ((size_t)(b * S_LEN + qrow + l16)) * DM + h * HD;
#pragma unroll
        for (int df = 0; df < 4; ++df) {
            const int d0 = df * 16 + quad * 4;
            u32x2 ov;
            ov.x = cvtpk(oacc0[df][0] * inv, oacc0[df][1] * inv);
            ov.y = cvtpk(oacc0[df][2] * inv, oacc0[df][3] * inv);
            *(u32x2*)(ows + rowbase + d0) = ov;
        }
    }
    {
        const float inv = 1.0f / lrow1;
        const size_t rowbase = ((size_t)(b * S_LEN + qrow + 64 + l16)) * DM + h * HD;
#pragma unroll
        for (int df = 0; df < 4; ++df) {
            const int d0 = df * 16 + quad * 4;
            u32x2 ov;
            ov.x = cvtpk(oacc1[df][0] * inv, oacc1[df][1] * inv);
            ov.y = cvtpk(oacc1[df][2] * inv, oacc1[df][3] * inv);
            *(u32x2*)(ows + rowbase + d0) = ov;
        }
    }
}

extern "C" void kernel_launch(void* const* d_in, const int* in_sizes, int n_in,
                              void* d_out, int out_size, void* d_ws, size_t ws_size,
                              hipStream_t stream) {
    const void* x = d_in[0];
    const void* w_qkv = d_in[1];
    const void* b_qkv = d_in[2];
    const void* w_out = d_in[3];
    const void* b_out = d_in[4];

    int* flag = (int*)d_ws;
    u16* xb = (u16*)d_ws + 8;                        // 8 MB
    u16* wqkvb = xb + (size_t)TOK * DM;              // 6 MB
    u16* woutb = wqkvb + (size_t)3 * DM * DM;        // 2 MB
    u16* qws = woutb + (size_t)DM * DM;              // (B,H,S,64) 8 MB
    u16* kws = qws + (size_t)NB * NH * S_LEN * HD;   // 8 MB
    u16* vT = kws + (size_t)NB * NH * S_LEN * HD;    // (B,H,64,S) 8 MB
    u16* ows = vT + (size_t)NB * NH * HD * S_LEN;    // attn out (B,S,DM) 8 MB
    float* tab = (float*)(ows + (size_t)TOK * DM);   // 16x2048 f32x4 = 512 KB

    detect_dtype<<<1, 256, 0, stream>>>((const u32*)x, flag);
    convert_all<<<(CONVTOT + TABN) / 256, 256, 0, stream>>>(
        x, w_qkv, w_out, xb, wqkvb, woutb, tab, flag);

    // fused QKV GEMM: q/k blocks (RoPE) and v blocks (transpose) as separate
    // template instantiations (lean regalloc, no runtime branch)
    gemm_k<1><<<dim3(16, TOK / 128), 256, 0, stream>>>(
        xb, wqkvb, b_qkv, nullptr, TOK, 3 * DM, DM, flag, 0, qws, kws, nullptr, tab);
    gemm_k<2><<<dim3(8, TOK / 128), 256, 0, stream>>>(
        xb, wqkvb, b_qkv, nullptr, TOK, 3 * DM, DM, flag, 0, nullptr, nullptr, vT, nullptr);
    // 1-D grid: id = qbr*32 + g, g=(b,h). 512 blocks x 256 threads.
    attn_kernel<<<dim3(16 * 32), 256, 0, stream>>>(qws, kws, vT, ows);
    gemm_k<0><<<dim3(DM / 128, TOK / 128), 256, 0, stream>>>(
        ows, woutb, b_out, d_out, TOK, DM, DM, flag, 1, nullptr, nullptr, nullptr, nullptr);
}

// Round 13
// 207.032 us; speedup vs baseline: 1.0708x; 1.0708x over previous
//
#include <hip/hip_runtime.h>
#include <stdint.h>

#define S_LEN 2048
#define NH 16
#define DM 1024
#define HD 64
#define NB 2
#define TOK (NB * S_LEN)  // 4096

typedef __attribute__((ext_vector_type(8))) short short8v;  // 8 bf16 = 4 VGPR
typedef __attribute__((ext_vector_type(4))) float f32x4;
typedef __attribute__((ext_vector_type(2))) unsigned int u32x2;
typedef unsigned short u16;
typedef unsigned int u32;

__device__ __forceinline__ float bf2f(u16 u) {
    u32 x = ((u32)u) << 16;
    return __builtin_bit_cast(float, x);
}
__device__ __forceinline__ u16 f2bf(float f) {  // RNE
    u32 u = __builtin_bit_cast(u32, f);
    return (u16)((u + 0x7FFFu + ((u >> 16) & 1u)) >> 16);
}
// pack 2 floats -> 2 bf16 in one instr (RNE); lo -> bits 15:0
__device__ __forceinline__ u32 cvtpk(float lo, float hi) {
    u32 r;
    asm("v_cvt_pk_bf16_f32 %0, %1, %2" : "=v"(r) : "v"(lo), "v"(hi));
    return r;
}

// async global->LDS, 16B per lane. LDS dest = wave-uniform base + lane*16 (HW).
__device__ __forceinline__ void gld_lds16(const void* g, void* lds_base_uniform) {
    auto gp = (const __attribute__((address_space(1))) u32*)(uintptr_t)g;
    auto lp = (__attribute__((address_space(3))) u32*)(uintptr_t)(u32)(uintptr_t)lds_base_uniform;
    __builtin_amdgcn_global_load_lds(gp, lp, 16, 0, 0);
}

// ---------------------------------------------------------------------------
// dtype sniffer: flag=1 if x is bf16, 0 if fp32.
// ---------------------------------------------------------------------------
__global__ void detect_dtype(const u32* __restrict__ xw, int* __restrict__ flag) {
    __shared__ int cnt[4];
    const int t = threadIdx.x;
    int c = 0;
#pragma unroll
    for (int j = 0; j < 16; ++j) {
        const u32 wd = xw[(t * 16 + j) * 64];
        const u32 e = (wd >> 7) & 0xFF;
        c += (e >= 0x58 && e <= 0x98) ? 1 : 0;
    }
#pragma unroll
    for (int off = 1; off < 64; off <<= 1) c += __shfl_xor(c, off);
    if ((t & 63) == 0) cnt[t >> 6] = c;
    __syncthreads();
    if (t == 0) flag[0] = (cnt[0] + cnt[1] + cnt[2] + cnt[3] >= 2600) ? 1 : 0;
}

// ---------------------------------------------------------------------------
// Fused fp32 -> bf16 conversion of x, w_qkv, w_out (copy-through when bf16)
// + RoPE table, PAIR-MAJOR layout for coalesced epilogue loads:
//   tabp[i2][s] = {cos(s*f(2*i2)), sin(s*f(2*i2)),
//                  cos(s*f(2*i2+1)), sin(s*f(2*i2+1))},  f(i)=10000^(-2i/64)
// i2 = d0/4 in [0,16). 16B/entry; lanes read consecutive s -> contiguous.
// ---------------------------------------------------------------------------
#define XCH (TOK * DM / 8)           // 524288
#define WQCH (3 * DM * DM / 8)       // 393216
#define WOCH (DM * DM / 8)           // 131072
#define CONVTOT (XCH + WQCH + WOCH)  // 1048576
#define TABN (S_LEN * 16)            // 32768 entries x 16B = 512 KB
__global__ __launch_bounds__(256) void convert_all(
    const void* __restrict__ xs, const void* __restrict__ wqs, const void* __restrict__ wos,
    u16* __restrict__ xd, u16* __restrict__ wqd, u16* __restrict__ wod,
    float* __restrict__ tab, const int* __restrict__ flagp) {
    int i = blockIdx.x * 256 + threadIdx.x;
    if (i >= CONVTOT) {  // table region
        const int e = i - CONVTOT;  // 0..32767
        const int s = e & 2047;
        const int i2 = e >> 11;  // 0..15
        const float fa = expf(-(float)(2 * i2) * 0.2878231366242557f);
        const float fb = expf(-(float)(2 * i2 + 1) * 0.2878231366242557f);
        float sa, ca, sb, cb;
        sincosf((float)s * fa, &sa, &ca);
        sincosf((float)s * fb, &sb, &cb);
        f32x4 tv = {ca, sa, cb, sb};
        *(f32x4*)(tab + (size_t)e * 4) = tv;
        return;
    }
    const void* src;
    u16* dst;
    if (i < XCH) {
        src = xs; dst = xd;
    } else if (i < XCH + WQCH) {
        src = wqs; dst = wqd; i -= XCH;
    } else {
        src = wos; dst = wod; i -= XCH + WQCH;
    }
    if (flagp[0]) {
        ((short8v*)dst)[i] = ((const short8v*)src)[i];
    } else {
        const f32x4 v0 = ((const f32x4*)src)[2 * i];
        const f32x4 v1 = ((const f32x4*)src)[2 * i + 1];
        short8v o;
#pragma unroll
        for (int q = 0; q < 4; ++q) o[q] = (short)f2bf(v0[q]);
#pragma unroll
        for (int q = 0; q < 4; ++q) o[4 + q] = (short)f2bf(v1[q]);
        ((short8v*)dst)[i] = o;
    }
}

// ---------------------------------------------------------------------------
// GEMM C[m,n] = sum_k A[m,k]*Bt[n,k] + bias[n]; bf16 in, fp32 accum.
// 128x128 tile, BK=32, 3-buffer counted-vmcnt pipeline (R7-verified).
// Compile-time MODE:
//   MODE 0: standard epilogue -> Cv (lane holds 4 consecutive n; 8B/16B
//           vector stores).
//   MODE 1 (q/k, grid.x=16): RoPE fused. Lane's 4 consecutive n = 2 rotation
//           pairs; coalesced pair-major table load; 8B stores into qws/kws
//           (B,H,S,64).
//   MODE 2 (v, grid.x=8, bn+=2048): MFMA operands flipped so lane holds 4
//           consecutive tokens at fixed d; 8B stores direct into vT (B,H,64,S).
// ---------------------------------------------------------------------------
template <int MODE>
__global__ __launch_bounds__(256) void gemm_k(
    const u16* __restrict__ A, const u16* __restrict__ Bt,
    const void* __restrict__ biasv, void* __restrict__ Cv,
    int M, int N, int K, const int* __restrict__ flagp, int out_flagged,
    u16* __restrict__ qws, u16* __restrict__ kws,
    u16* __restrict__ vT, const float* __restrict__ tab) {
    __shared__ __align__(16) u16 lA[3][128 * 32];
    __shared__ __align__(16) u16 lB[3][128 * 32];
    const int fl = flagp[0];
    const int fo = out_flagged ? fl : 1;  // MODE 0: 1 => bf16 output

    const int tid = threadIdx.x;
    const int w = __builtin_amdgcn_readfirstlane(tid >> 6);
    const int lane = tid & 63;
    const int quad = lane >> 4;
    const int l16 = lane & 15;
    const int bm = blockIdx.y * 128;
    const int bn = (MODE == 2 ? 2048 : 0) + blockIdx.x * 128;
    const int wm = (w >> 1) * 64;
    const int wn = (w & 1) * 64;

    f32x4 acc[4][4];
#pragma unroll
    for (int i = 0; i < 4; ++i)
#pragma unroll
        for (int j = 0; j < 4; ++j) acc[i][j] = {0.f, 0.f, 0.f, 0.f};

    const int kiters = K >> 5;
#define GEMM_STAGE(kk, buf)                                                            \
    {                                                                                  \
        _Pragma("unroll") for (int c = 0; c < 2; ++c) {                                \
            const int chunk = w * 2 + c;                                               \
            const int off = chunk * 1024 + lane * 16;                                  \
            const int m_ = off >> 6;                                                   \
            const int kb_ = off & 63;                                                  \
            gld_lds16((const char*)(A + (size_t)(bm + m_) * K + (kk) * 32) + kb_,      \
                      (char*)&lA[buf][0] + chunk * 1024);                              \
            gld_lds16((const char*)(Bt + (size_t)(bn + m_) * K + (kk) * 32) + kb_,     \
                      (char*)&lB[buf][0] + chunk * 1024);                              \
        }                                                                              \
    }

    GEMM_STAGE(0, 0);
    if (kiters > 1) GEMM_STAGE(1, 1);
    int cur = 0;
    for (int kk = 0; kk < kiters; ++kk) {
        if (kk + 1 < kiters) {
            asm volatile("s_waitcnt vmcnt(4)" ::: "memory");
        } else {
            asm volatile("s_waitcnt vmcnt(0)" ::: "memory");
        }
        __builtin_amdgcn_s_barrier();
        if (kk + 2 < kiters) {
            const int nb = (cur + 2 >= 3) ? cur - 1 : cur + 2;
            GEMM_STAGE(kk + 2, nb);
        }

        short8v af[4], bf[4];
#pragma unroll
        for (int t = 0; t < 4; ++t) {
            af[t] = *(const short8v*)&lA[cur][(wm + t * 16 + l16) * 32 + quad * 8];
            bf[t] = *(const short8v*)&lB[cur][(wn + t * 16 + l16) * 32 + quad * 8];
        }
        __builtin_amdgcn_s_setprio(1);
        if constexpr (MODE == 2) {  // rows <- m: lane holds 4 consecutive tokens
#pragma unroll
            for (int i = 0; i < 4; ++i)
#pragma unroll
                for (int j = 0; j < 4; ++j)
                    acc[i][j] =
                        __builtin_amdgcn_mfma_f32_16x16x32_bf16(af[i], bf[j], acc[i][j], 0, 0, 0);
        } else {  // rows <- n: lane holds 4 consecutive n
#pragma unroll
            for (int i = 0; i < 4; ++i)
#pragma unroll
                for (int j = 0; j < 4; ++j)
                    acc[i][j] =
                        __builtin_amdgcn_mfma_f32_16x16x32_bf16(bf[j], af[i], acc[i][j], 0, 0, 0);
        }
        __builtin_amdgcn_s_setprio(0);
        cur = (cur == 2) ? 0 : cur + 1;
    }
#undef GEMM_STAGE

    if constexpr (MODE == 0) {
        // acc[i][j] = C[m=bm+wm+i*16+l16][n=bn+wn+j*16+quad*4+r]
#pragma unroll
        for (int j = 0; j < 4; ++j) {
            const int n0 = bn + wn + j * 16 + quad * 4;
            float bv0, bv1, bv2, bv3;
            if (fl) {
                const u32x2 bw = *(const u32x2*)((const u16*)biasv + n0);
                bv0 = bf2f((u16)(bw.x & 0xffff));
                bv1 = bf2f((u16)(bw.x >> 16));
                bv2 = bf2f((u16)(bw.y & 0xffff));
                bv3 = bf2f((u16)(bw.y >> 16));
            } else {
                const f32x4 bw = *(const f32x4*)((const float*)biasv + n0);
                bv0 = bw[0]; bv1 = bw[1]; bv2 = bw[2]; bv3 = bw[3];
            }
#pragma unroll
            for (int i = 0; i < 4; ++i) {
                const size_t base = (size_t)(bm + wm + i * 16 + l16) * N + n0;
                const float v0 = acc[i][j][0] + bv0, v1 = acc[i][j][1] + bv1;
                const float v2 = acc[i][j][2] + bv2, v3 = acc[i][j][3] + bv3;
                if (fo) {
                    u32x2 ov;
                    ov.x = cvtpk(v0, v1);
                    ov.y = cvtpk(v2, v3);
                    *(u32x2*)((u16*)Cv + base) = ov;
                } else {
                    f32x4 ov = {v0, v1, v2, v3};
                    *(f32x4*)((float*)Cv + base) = ov;
                }
            }
        }
    } else if constexpr (MODE == 2) {
        // acc[i][j] = C[m=bm+wm+i*16+quad*4+r][n=bn+wn+j*16+l16]
        // 4 consecutive tokens at fixed d -> 8B stores into vT (B,H,64,S)
#pragma unroll
        for (int j = 0; j < 4; ++j) {
            const int n = bn + wn + j * 16 + l16;
            const float bv = fl ? bf2f(((const u16*)biasv)[n]) : ((const float*)biasv)[n];
            const int vcol = n - 2048;
            const int hh = vcol >> 6, d = vcol & 63;
#pragma unroll
            for (int i = 0; i < 4; ++i) {
                const int m0 = bm + wm + i * 16 + quad * 4;
                const int bb = m0 >> 11, s0 = m0 & 2047;
                u32x2 ov;
                ov.x = cvtpk(acc[i][j][0] + bv, acc[i][j][1] + bv);
                ov.y = cvtpk(acc[i][j][2] + bv, acc[i][j][3] + bv);
                *(u32x2*)(vT + ((size_t)((bb * NH + hh) * HD + d)) * S_LEN + s0) = ov;
            }
        }
    } else {
        // q/k: acc[i][j] = C[m=bm+wm+i*16+l16][n=bn+wn+j*16+quad*4+r]
        // 4 consecutive n = 2 RoPE pairs; pair-major coalesced table load
        const bool isq = (blockIdx.x < 8);
        u16* outp = isq ? qws : kws;
#pragma unroll
        for (int j = 0; j < 4; ++j) {
            const int n0 = bn + wn + j * 16 + quad * 4;
            float bv0, bv1, bv2, bv3;
            if (fl) {
                const u32x2 bw = *(const u32x2*)((const u16*)biasv + n0);
                bv0 = bf2f((u16)(bw.x & 0xffff));
                bv1 = bf2f((u16)(bw.x >> 16));
                bv2 = bf2f((u16)(bw.y & 0xffff));
                bv3 = bf2f((u16)(bw.y >> 16));
            } else {
                const f32x4 bw = *(const f32x4*)((const float*)biasv + n0);
                bv0 = bw[0]; bv1 = bw[1]; bv2 = bw[2]; bv3 = bw[3];
            }
            const int nc = n0 & 1023;  // strip q/k bit
            const int hh = nc >> 6;    // head
            const int d0 = nc & 63;    // 4-aligned dim offset
            const int i2u = d0 >> 2;   // pair-major table row
#pragma unroll
            for (int i = 0; i < 4; ++i) {
                const int m = bm + wm + i * 16 + l16;
                const int bb = m >> 11, s = m & 2047;
                // lanes have consecutive s -> 16B x 16 lanes contiguous
                const f32x4 cs4 = *(const f32x4*)(tab + ((size_t)i2u * S_LEN + s) * 4);
                const float v0 = acc[i][j][0] + bv0, v1 = acc[i][j][1] + bv1;
                const float v2 = acc[i][j][2] + bv2, v3 = acc[i][j][3] + bv3;
                const float o0 = v0 * cs4[0] - v1 * cs4[1];
                const float o1 = v0 * cs4[1] + v1 * cs4[0];
                const float o2 = v2 * cs4[2] - v3 * cs4[3];
                const float o3 = v2 * cs4[3] + v3 * cs4[2];
                u32x2 ov;
                ov.x = cvtpk(o0, o1);
                ov.y = cvtpk(o2, o3);
                *(u32x2*)(outp + ((size_t)((bb * NH + hh) * S_LEN + s)) * HD + d0) = ov;
            }
        }
    }
}

// ---------------------------------------------------------------------------
// Flash attention (R9-measured structure, reverted from R11/R12 regression).
// 256-thread blocks = 4 waves x 16 q-rows (64 rows/block). Grid 1024:
// id = qbr*32 + g, g=(b,h) low 5 bits -> XCD pin; qb = 31-qbr (longest
// first). Counted-vmcnt K dbuf + V single; swizzled LDS; cvt_pk epilogue.
// NEW: defer-max (T13, HK THR=8): when the tile max is within 8 of the
// running max across all lanes, skip the O-rescale (keep m_old; P <= e^8,
// bf16/f32 headroom fine). Saves alpha-exp + 16 v_mul on most iterations.
// ---------------------------------------------------------------------------
__global__ __launch_bounds__(256, 4) void attn_kernel(
    const u16* __restrict__ qws, const u16* __restrict__ kws,
    const u16* __restrict__ vT, u16* __restrict__ ows) {
    __shared__ __align__(16) u16 kl[2][64 * 64];    // K dbuf, 16 KB
    __shared__ __align__(16) u16 vl[64 * 64];       // V single, 8 KB
    __shared__ __align__(16) u32 pl32[4][16 * 36];  // per-wave P, 9216 B
    const int t = threadIdx.x;
    const int w = __builtin_amdgcn_readfirstlane(t >> 6);
    const int lane = t & 63;
    const int quad = lane >> 4;
    const int l16 = lane & 15;

    const int id = blockIdx.x;
    const int g = id & 31;          // (b,h) -> XCD pin g%8
    const int qb = 31 - (id >> 5);  // longest-first
    const int h = g & 15, b = g >> 4;
    const int q0 = qb * 64 + w * 16;  // wave's 16 q-rows

    const size_t bh = (size_t)(b * NH + h);
    const u16* qbp = qws + bh * (size_t)S_LEN * HD;
    const u16* kb = kws + bh * (size_t)S_LEN * HD;
    const u16* vb = vT + bh * (size_t)HD * S_LEN;

    // staging geometry: wave w stages rows [w*8+s*32 .. +7], lane -> 16B
    const int r0 = lane >> 3;                // row within 8-row group
    const int srcc = (lane & 7) ^ r0;        // pre-swizzled col16
    const int xorb = (l16 & 7) << 4;         // read-side swizzle XOR

    short8v qf[2];
#pragma unroll
    for (int hf = 0; hf < 2; ++hf)
        qf[hf] = *(const short8v*)(qbp + (size_t)(q0 + l16) * HD + hf * 32 + quad * 8);

    f32x4 oaccT[4];  // row = d (quad*4+r), col = q (l16)
#pragma unroll
    for (int d = 0; d < 4; ++d) oaccT[d] = {0.f, 0.f, 0.f, 0.f};
    float mrow = -__builtin_inff();
    float lrow = 0.f;

    // prologue: stage K[0]
#pragma unroll
    for (int s = 0; s < 2; ++s) {
        const int row = w * 8 + s * 32 + r0;
        gld_lds16(kb + (size_t)row * HD + srcc * 8, (char*)&kl[0][0] + w * 1024 + s * 4096);
    }

    int cur = 0;
    for (int kt = 0; kt <= qb; ++kt) {
        __syncthreads();  // K[kt] staged by all; V free; kl[cur^1] free
        // issue V[kt] FIRST (oldest in vm queue), then K[kt+1]
#pragma unroll
        for (int s = 0; s < 2; ++s) {
            const int row = w * 8 + s * 32 + r0;
            gld_lds16(vb + (size_t)row * S_LEN + kt * 64 + srcc * 8,
                      (char*)&vl[0] + w * 1024 + s * 4096);
        }
        if (kt < qb) {
#pragma unroll
            for (int s = 0; s < 2; ++s) {
                const int row = w * 8 + s * 32 + r0;
                gld_lds16(kb + (size_t)((kt + 1) * 64 + row) * HD + srcc * 8,
                          (char*)&kl[cur ^ 1][0] + w * 1024 + s * 4096);
            }
        }
        const char* Kb = (const char*)&kl[cur][0];

        // S^T sub-tiles: row = k (quad*4+r within sub), col = q (l16)
        f32x4 s4[4];
        __builtin_amdgcn_s_setprio(1);
#pragma unroll
        for (int sub = 0; sub < 4; ++sub) {
            const int lin = (sub * 16 + l16) * 128 + quad * 16;
            const short8v k0 = *(const short8v*)(Kb + (lin ^ xorb));
            const short8v k1 = *(const short8v*)(Kb + ((lin + 64) ^ xorb));
            f32x4 a = {0.f, 0.f, 0.f, 0.f};
            a = __builtin_amdgcn_mfma_f32_16x16x32_bf16(k0, qf[0], a, 0, 0, 0);
            a = __builtin_amdgcn_mfma_f32_16x16x32_bf16(k1, qf[1], a, 0, 0, 0);
            s4[sub] = a;
        }
        __builtin_amdgcn_s_setprio(0);
        float sv[16];
#pragma unroll
        for (int sub = 0; sub < 4; ++sub)
#pragma unroll
            for (int r = 0; r < 4; ++r) sv[sub * 4 + r] = s4[sub][r] * 0.125f;
        if (kt == qb) {  // masked diagonal tile: k > q -> -inf
            const int qloc = w * 16 + l16;
#pragma unroll
            for (int sub = 0; sub < 4; ++sub)
#pragma unroll
                for (int r = 0; r < 4; ++r)
                    if (sub * 16 + quad * 4 + r > qloc) sv[sub * 4 + r] = -__builtin_inff();
        }
        // per-q-row max: 15 in-lane (tree) + 2 cross-lane
        float a0 = fmaxf(sv[0], sv[1]), a1 = fmaxf(sv[2], sv[3]);
        float a2 = fmaxf(sv[4], sv[5]), a3 = fmaxf(sv[6], sv[7]);
        float a4 = fmaxf(sv[8], sv[9]), a5 = fmaxf(sv[10], sv[11]);
        float a6 = fmaxf(sv[12], sv[13]), a7 = fmaxf(sv[14], sv[15]);
        a0 = fmaxf(a0, a1); a2 = fmaxf(a2, a3);
        a4 = fmaxf(a4, a5); a6 = fmaxf(a6, a7);
        a0 = fmaxf(a0, a2); a4 = fmaxf(a4, a6);
        float mx = fmaxf(a0, a4);
        mx = fmaxf(mx, __shfl_xor(mx, 16));
        mx = fmaxf(mx, __shfl_xor(mx, 32));
        // defer-max (T13): rescale only when some row's max grew by > 8
        if (!__all(mx - mrow <= 8.0f)) {
            const float mnew = fmaxf(mrow, mx);
            const float alpha = __expf(mrow - mnew);
            mrow = mnew;
            lrow *= alpha;
#pragma unroll
            for (int d = 0; d < 4; ++d) oaccT[d] *= alpha;
        }
        float p[16];
#pragma unroll
        for (int i = 0; i < 16; ++i) p[i] = __expf(sv[i] - mrow);
        float b0 = p[0] + p[1], b1 = p[2] + p[3], b2 = p[4] + p[5], b3 = p[6] + p[7];
        float b4 = p[8] + p[9], b5 = p[10] + p[11], b6 = p[12] + p[13], b7 = p[14] + p[15];
        b0 += b1; b2 += b3; b4 += b5; b6 += b7;
        b0 += b2; b4 += b6;
        float ps = b0 + b4;
        ps += __shfl_xor(ps, 16);
        ps += __shfl_xor(ps, 32);
        lrow += ps;
        // pack P[q=l16][k] via cvt_pk; 4x b64 writes (stride-36 rows)
        u32* prow = &pl32[w][l16 * 36];
#pragma unroll
        for (int sub = 0; sub < 4; ++sub) {
            u32x2 pw;
            pw.x = cvtpk(p[sub * 4 + 0], p[sub * 4 + 1]);
            pw.y = cvtpk(p[sub * 4 + 2], p[sub * 4 + 3]);
            *(u32x2*)&prow[sub * 8 + quad * 2] = pw;
        }
        asm volatile("s_waitcnt lgkmcnt(0)" ::: "memory");  // P visible (DS in-order)
        // wait own V chunks (K[kt+1] stays in flight), then join
        if (kt < qb) {
            asm volatile("s_waitcnt vmcnt(2)" ::: "memory");
        } else {
            asm volatile("s_waitcnt vmcnt(0)" ::: "memory");
        }
        __builtin_amdgcn_s_barrier();
        asm volatile("" ::: "memory");
        // PV: B-frag = P[q][c2*32 + quad*8 .. +7]; A-frag = V^T rows
        __builtin_amdgcn_s_setprio(1);
#pragma unroll
        for (int c2 = 0; c2 < 2; ++c2) {
            const short8v pf = *(const short8v*)&pl32[w][l16 * 36 + c2 * 16 + quad * 4];
#pragma unroll
            for (int d = 0; d < 4; ++d) {
                const int lin = (d * 16 + l16) * 128 + c2 * 64 + quad * 16;
                const short8v vfd = *(const short8v*)((const char*)&vl[0] + (lin ^ xorb));
                oaccT[d] = __builtin_amdgcn_mfma_f32_16x16x32_bf16(vfd, pf, oaccT[d], 0, 0, 0);
            }
        }
        __builtin_amdgcn_s_setprio(0);
        cur ^= 1;
    }

    // epilogue: O[q][d], q = q0+l16, d = df*16+quad*4+r -> 8B packed stores
    const float inv = 1.0f / lrow;
    const size_t rowbase = ((size_t)(b * S_LEN + q0 + l16)) * DM + h * HD;
#pragma unroll
    for (int df = 0; df < 4; ++df) {
        const int d0 = df * 16 + quad * 4;
        u32x2 ov;
        ov.x = cvtpk(oaccT[df][0] * inv, oaccT[df][1] * inv);
        ov.y = cvtpk(oaccT[df][2] * inv, oaccT[df][3] * inv);
        *(u32x2*)(ows + rowbase + d0) = ov;
    }
}

extern "C" void kernel_launch(void* const* d_in, const int* in_sizes, int n_in,
                              void* d_out, int out_size, void* d_ws, size_t ws_size,
                              hipStream_t stream) {
    const void* x = d_in[0];
    const void* w_qkv = d_in[1];
    const void* b_qkv = d_in[2];
    const void* w_out = d_in[3];
    const void* b_out = d_in[4];

    int* flag = (int*)d_ws;
    u16* xb = (u16*)d_ws + 8;                        // 8 MB
    u16* wqkvb = xb + (size_t)TOK * DM;              // 6 MB
    u16* woutb = wqkvb + (size_t)3 * DM * DM;        // 2 MB
    u16* qws = woutb + (size_t)DM * DM;              // (B,H,S,64) 8 MB
    u16* kws = qws + (size_t)NB * NH * S_LEN * HD;   // 8 MB
    u16* vT = kws + (size_t)NB * NH * S_LEN * HD;    // (B,H,64,S) 8 MB
    u16* ows = vT + (size_t)NB * NH * HD * S_LEN;    // attn out (B,S,DM) 8 MB
    float* tab = (float*)(ows + (size_t)TOK * DM);   // 16x2048 f32x4 = 512 KB

    detect_dtype<<<1, 256, 0, stream>>>((const u32*)x, flag);
    convert_all<<<(CONVTOT + TABN) / 256, 256, 0, stream>>>(
        x, w_qkv, w_out, xb, wqkvb, woutb, tab, flag);

    // fused QKV GEMM: q/k blocks (RoPE) and v blocks (transpose) as separate
    // template instantiations (lean regalloc, no runtime branch)
    gemm_k<1><<<dim3(16, TOK / 128), 256, 0, stream>>>(
        xb, wqkvb, b_qkv, nullptr, TOK, 3 * DM, DM, flag, 0, qws, kws, nullptr, tab);
    gemm_k<2><<<dim3(8, TOK / 128), 256, 0, stream>>>(
        xb, wqkvb, b_qkv, nullptr, TOK, 3 * DM, DM, flag, 0, nullptr, nullptr, vT, nullptr);
    // 1-D grid: id = qbr*32 + g, g=(b,h). 1024 blocks x 256 threads.
    attn_kernel<<<dim3(32 * 32), 256, 0, stream>>>(qws, kws, vT, ows);
    gemm_k<0><<<dim3(DM / 128, TOK / 128), 256, 0, stream>>>(
        ows, woutb, b_out, d_out, TOK, DM, DM, flag, 1, nullptr, nullptr, nullptr, nullptr);
}

// Round 14
// 201.881 us; speedup vs baseline: 1.0981x; 1.0255x over previous
//
#include <hip/hip_runtime.h>
#include <stdint.h>

#define S_LEN 2048
#define NH 16
#define DM 1024
#define HD 64
#define NB 2
#define TOK (NB * S_LEN)  // 4096

typedef __attribute__((ext_vector_type(8))) short short8v;  // 8 bf16 = 4 VGPR
typedef __attribute__((ext_vector_type(4))) float f32x4;
typedef __attribute__((ext_vector_type(2))) unsigned int u32x2;
typedef unsigned short u16;
typedef unsigned int u32;

__device__ __forceinline__ float bf2f(u16 u) {
    u32 x = ((u32)u) << 16;
    return __builtin_bit_cast(float, x);
}
__device__ __forceinline__ u16 f2bf(float f) {  // RNE
    u32 u = __builtin_bit_cast(u32, f);
    return (u16)((u + 0x7FFFu + ((u >> 16) & 1u)) >> 16);
}
// pack 2 floats -> 2 bf16 in one instr (RNE); lo -> bits 15:0
__device__ __forceinline__ u32 cvtpk(float lo, float hi) {
    u32 r;
    asm("v_cvt_pk_bf16_f32 %0, %1, %2" : "=v"(r) : "v"(lo), "v"(hi));
    return r;
}

// async global->LDS, 16B per lane. LDS dest = wave-uniform base + lane*16 (HW).
__device__ __forceinline__ void gld_lds16(const void* g, void* lds_base_uniform) {
    auto gp = (const __attribute__((address_space(1))) u32*)(uintptr_t)g;
    auto lp = (__attribute__((address_space(3))) u32*)(uintptr_t)(u32)(uintptr_t)lds_base_uniform;
    __builtin_amdgcn_global_load_lds(gp, lp, 16, 0, 0);
}

// ---------------------------------------------------------------------------
// dtype sniffer: flag=1 if x is bf16, 0 if fp32.
// ---------------------------------------------------------------------------
__global__ void detect_dtype(const u32* __restrict__ xw, int* __restrict__ flag) {
    __shared__ int cnt[4];
    const int t = threadIdx.x;
    int c = 0;
#pragma unroll
    for (int j = 0; j < 16; ++j) {
        const u32 wd = xw[(t * 16 + j) * 64];
        const u32 e = (wd >> 7) & 0xFF;
        c += (e >= 0x58 && e <= 0x98) ? 1 : 0;
    }
#pragma unroll
    for (int off = 1; off < 64; off <<= 1) c += __shfl_xor(c, off);
    if ((t & 63) == 0) cnt[t >> 6] = c;
    __syncthreads();
    if (t == 0) flag[0] = (cnt[0] + cnt[1] + cnt[2] + cnt[3] >= 2600) ? 1 : 0;
}

// ---------------------------------------------------------------------------
// Fused fp32 -> bf16 conversion of x, w_qkv, w_out (copy-through when bf16)
// + RoPE table, PAIR-MAJOR layout for coalesced epilogue loads:
//   tabp[i2][s] = {cos(s*f(2*i2)), sin(s*f(2*i2)),
//                  cos(s*f(2*i2+1)), sin(s*f(2*i2+1))},  f(i)=10000^(-2i/64)
// i2 = d0/4 in [0,16). 16B/entry; lanes read consecutive s -> contiguous.
// ---------------------------------------------------------------------------
#define XCH (TOK * DM / 8)           // 524288
#define WQCH (3 * DM * DM / 8)       // 393216
#define WOCH (DM * DM / 8)           // 131072
#define CONVTOT (XCH + WQCH + WOCH)  // 1048576
#define TABN (S_LEN * 16)            // 32768 entries x 16B = 512 KB
__global__ __launch_bounds__(256) void convert_all(
    const void* __restrict__ xs, const void* __restrict__ wqs, const void* __restrict__ wos,
    u16* __restrict__ xd, u16* __restrict__ wqd, u16* __restrict__ wod,
    float* __restrict__ tab, const int* __restrict__ flagp) {
    int i = blockIdx.x * 256 + threadIdx.x;
    if (i >= CONVTOT) {  // table region
        const int e = i - CONVTOT;  // 0..32767
        const int s = e & 2047;
        const int i2 = e >> 11;  // 0..15
        const float fa = expf(-(float)(2 * i2) * 0.2878231366242557f);
        const float fb = expf(-(float)(2 * i2 + 1) * 0.2878231366242557f);
        float sa, ca, sb, cb;
        sincosf((float)s * fa, &sa, &ca);
        sincosf((float)s * fb, &sb, &cb);
        f32x4 tv = {ca, sa, cb, sb};
        *(f32x4*)(tab + (size_t)e * 4) = tv;
        return;
    }
    const void* src;
    u16* dst;
    if (i < XCH) {
        src = xs; dst = xd;
    } else if (i < XCH + WQCH) {
        src = wqs; dst = wqd; i -= XCH;
    } else {
        src = wos; dst = wod; i -= XCH + WQCH;
    }
    if (flagp[0]) {
        ((short8v*)dst)[i] = ((const short8v*)src)[i];
    } else {
        const f32x4 v0 = ((const f32x4*)src)[2 * i];
        const f32x4 v1 = ((const f32x4*)src)[2 * i + 1];
        short8v o;
#pragma unroll
        for (int q = 0; q < 4; ++q) o[q] = (short)f2bf(v0[q]);
#pragma unroll
        for (int q = 0; q < 4; ++q) o[4 + q] = (short)f2bf(v1[q]);
        ((short8v*)dst)[i] = o;
    }
}

// ---------------------------------------------------------------------------
// GEMM C[m,n] = sum_k A[m,k]*Bt[n,k] + bias[n]; bf16 in, fp32 accum.
// 128x128 tile, BK=32, 3-buffer counted-vmcnt pipeline (R7-verified).
//
// XCD RECTANGLE SWIZZLE (T1): 1-D grid; id%8 = XCD under round-robin
// dispatch. Each XCD owns an 8y x XW-x rectangle of tiles:
//   xcd=id&7; j=id>>3; y=(xcd>>1)*8+(j&7); x=(xcd&1)*XW+(j>>3)
// Per-XCD working set = A 2MB + B <=2MB <= 4MB L2 (was: all 32 A-panels =
// 8MB streaming through 4MB L2 -> ~45MB FETCH vs ~12MB compulsory).
//
// Compile-time MODE:
//   MODE 0 (grid 256, XW=4): standard epilogue -> Cv.
//   MODE 1 (grid 512, XW=8): RoPE fused; 8B stores into qws/kws (B,H,S,64).
//   MODE 2 (grid 256, XW=4, bn+=2048): MFMA flipped; lane holds 4
//           consecutive tokens at fixed d; 8B stores into vT (B,H,64,S).
// ---------------------------------------------------------------------------
template <int MODE>
__global__ __launch_bounds__(256) void gemm_k(
    const u16* __restrict__ A, const u16* __restrict__ Bt,
    const void* __restrict__ biasv, void* __restrict__ Cv,
    int M, int N, int K, const int* __restrict__ flagp, int out_flagged,
    u16* __restrict__ qws, u16* __restrict__ kws,
    u16* __restrict__ vT, const float* __restrict__ tab) {
    __shared__ __align__(16) u16 lA[3][128 * 32];
    __shared__ __align__(16) u16 lB[3][128 * 32];
    const int fl = flagp[0];
    const int fo = out_flagged ? fl : 1;  // MODE 0: 1 => bf16 output

    const int tid = threadIdx.x;
    const int w = __builtin_amdgcn_readfirstlane(tid >> 6);
    const int lane = tid & 63;
    const int quad = lane >> 4;
    const int l16 = lane & 15;

    // XCD rectangle swizzle (all grids are multiples of 8)
    constexpr int XW = (MODE == 1) ? 8 : 4;  // x-tiles per XCD rectangle
    const int id = blockIdx.x;
    const int xcd = id & 7;
    const int j = id >> 3;
    const int by = (xcd >> 1) * 8 + (j & 7);
    const int bx = (xcd & 1) * XW + (j >> 3);

    const int bm = by * 128;
    const int bn = (MODE == 2 ? 2048 : 0) + bx * 128;
    const int wm = (w >> 1) * 64;
    const int wn = (w & 1) * 64;

    f32x4 acc[4][4];
#pragma unroll
    for (int i = 0; i < 4; ++i)
#pragma unroll
        for (int jj = 0; jj < 4; ++jj) acc[i][jj] = {0.f, 0.f, 0.f, 0.f};

    const int kiters = K >> 5;
#define GEMM_STAGE(kk, buf)                                                            \
    {                                                                                  \
        _Pragma("unroll") for (int c = 0; c < 2; ++c) {                                \
            const int chunk = w * 2 + c;                                               \
            const int off = chunk * 1024 + lane * 16;                                  \
            const int m_ = off >> 6;                                                   \
            const int kb_ = off & 63;                                                  \
            gld_lds16((const char*)(A + (size_t)(bm + m_) * K + (kk) * 32) + kb_,      \
                      (char*)&lA[buf][0] + chunk * 1024);                              \
            gld_lds16((const char*)(Bt + (size_t)(bn + m_) * K + (kk) * 32) + kb_,     \
                      (char*)&lB[buf][0] + chunk * 1024);                              \
        }                                                                              \
    }

    GEMM_STAGE(0, 0);
    if (kiters > 1) GEMM_STAGE(1, 1);
    int cur = 0;
    for (int kk = 0; kk < kiters; ++kk) {
        if (kk + 1 < kiters) {
            asm volatile("s_waitcnt vmcnt(4)" ::: "memory");
        } else {
            asm volatile("s_waitcnt vmcnt(0)" ::: "memory");
        }
        __builtin_amdgcn_s_barrier();
        if (kk + 2 < kiters) {
            const int nb = (cur + 2 >= 3) ? cur - 1 : cur + 2;
            GEMM_STAGE(kk + 2, nb);
        }

        short8v af[4], bf[4];
#pragma unroll
        for (int t = 0; t < 4; ++t) {
            af[t] = *(const short8v*)&lA[cur][(wm + t * 16 + l16) * 32 + quad * 8];
            bf[t] = *(const short8v*)&lB[cur][(wn + t * 16 + l16) * 32 + quad * 8];
        }
        __builtin_amdgcn_s_setprio(1);
        if constexpr (MODE == 2) {  // rows <- m: lane holds 4 consecutive tokens
#pragma unroll
            for (int i = 0; i < 4; ++i)
#pragma unroll
                for (int jj = 0; jj < 4; ++jj)
                    acc[i][jj] =
                        __builtin_amdgcn_mfma_f32_16x16x32_bf16(af[i], bf[jj], acc[i][jj], 0, 0, 0);
        } else {  // rows <- n: lane holds 4 consecutive n
#pragma unroll
            for (int i = 0; i < 4; ++i)
#pragma unroll
                for (int jj = 0; jj < 4; ++jj)
                    acc[i][jj] =
                        __builtin_amdgcn_mfma_f32_16x16x32_bf16(bf[jj], af[i], acc[i][jj], 0, 0, 0);
        }
        __builtin_amdgcn_s_setprio(0);
        cur = (cur == 2) ? 0 : cur + 1;
    }
#undef GEMM_STAGE

    if constexpr (MODE == 0) {
        // acc[i][j] = C[m=bm+wm+i*16+l16][n=bn+wn+j*16+quad*4+r]
#pragma unroll
        for (int jj = 0; jj < 4; ++jj) {
            const int n0 = bn + wn + jj * 16 + quad * 4;
            float bv0, bv1, bv2, bv3;
            if (fl) {
                const u32x2 bw = *(const u32x2*)((const u16*)biasv + n0);
                bv0 = bf2f((u16)(bw.x & 0xffff));
                bv1 = bf2f((u16)(bw.x >> 16));
                bv2 = bf2f((u16)(bw.y & 0xffff));
                bv3 = bf2f((u16)(bw.y >> 16));
            } else {
                const f32x4 bw = *(const f32x4*)((const float*)biasv + n0);
                bv0 = bw[0]; bv1 = bw[1]; bv2 = bw[2]; bv3 = bw[3];
            }
#pragma unroll
            for (int i = 0; i < 4; ++i) {
                const size_t base = (size_t)(bm + wm + i * 16 + l16) * N + n0;
                const float v0 = acc[i][jj][0] + bv0, v1 = acc[i][jj][1] + bv1;
                const float v2 = acc[i][jj][2] + bv2, v3 = acc[i][jj][3] + bv3;
                if (fo) {
                    u32x2 ov;
                    ov.x = cvtpk(v0, v1);
                    ov.y = cvtpk(v2, v3);
                    *(u32x2*)((u16*)Cv + base) = ov;
                } else {
                    f32x4 ov = {v0, v1, v2, v3};
                    *(f32x4*)((float*)Cv + base) = ov;
                }
            }
        }
    } else if constexpr (MODE == 2) {
        // acc[i][j] = C[m=bm+wm+i*16+quad*4+r][n=bn+wn+j*16+l16]
        // 4 consecutive tokens at fixed d -> 8B stores into vT (B,H,64,S)
#pragma unroll
        for (int jj = 0; jj < 4; ++jj) {
            const int n = bn + wn + jj * 16 + l16;
            const float bv = fl ? bf2f(((const u16*)biasv)[n]) : ((const float*)biasv)[n];
            const int vcol = n - 2048;
            const int hh = vcol >> 6, d = vcol & 63;
#pragma unroll
            for (int i = 0; i < 4; ++i) {
                const int m0 = bm + wm + i * 16 + quad * 4;
                const int bb = m0 >> 11, s0 = m0 & 2047;
                u32x2 ov;
                ov.x = cvtpk(acc[i][jj][0] + bv, acc[i][jj][1] + bv);
                ov.y = cvtpk(acc[i][jj][2] + bv, acc[i][jj][3] + bv);
                *(u32x2*)(vT + ((size_t)((bb * NH + hh) * HD + d)) * S_LEN + s0) = ov;
            }
        }
    } else {
        // q/k: acc[i][j] = C[m=bm+wm+i*16+l16][n=bn+wn+j*16+quad*4+r]
        // 4 consecutive n = 2 RoPE pairs; pair-major coalesced table load
        const bool isq = (bx < 8);
        u16* outp = isq ? qws : kws;
#pragma unroll
        for (int jj = 0; jj < 4; ++jj) {
            const int n0 = bn + wn + jj * 16 + quad * 4;
            float bv0, bv1, bv2, bv3;
            if (fl) {
                const u32x2 bw = *(const u32x2*)((const u16*)biasv + n0);
                bv0 = bf2f((u16)(bw.x & 0xffff));
                bv1 = bf2f((u16)(bw.x >> 16));
                bv2 = bf2f((u16)(bw.y & 0xffff));
                bv3 = bf2f((u16)(bw.y >> 16));
            } else {
                const f32x4 bw = *(const f32x4*)((const float*)biasv + n0);
                bv0 = bw[0]; bv1 = bw[1]; bv2 = bw[2]; bv3 = bw[3];
            }
            const int nc = n0 & 1023;  // strip q/k bit
            const int hh = nc >> 6;    // head
            const int d0 = nc & 63;    // 4-aligned dim offset
            const int i2u = d0 >> 2;   // pair-major table row
#pragma unroll
            for (int i = 0; i < 4; ++i) {
                const int m = bm + wm + i * 16 + l16;
                const int bb = m >> 11, s = m & 2047;
                // lanes have consecutive s -> 16B x 16 lanes contiguous
                const f32x4 cs4 = *(const f32x4*)(tab + ((size_t)i2u * S_LEN + s) * 4);
                const float v0 = acc[i][jj][0] + bv0, v1 = acc[i][jj][1] + bv1;
                const float v2 = acc[i][jj][2] + bv2, v3 = acc[i][jj][3] + bv3;
                const float o0 = v0 * cs4[0] - v1 * cs4[1];
                const float o1 = v0 * cs4[1] + v1 * cs4[0];
                const float o2 = v2 * cs4[2] - v3 * cs4[3];
                const float o3 = v2 * cs4[3] + v3 * cs4[2];
                u32x2 ov;
                ov.x = cvtpk(o0, o1);
                ov.y = cvtpk(o2, o3);
                *(u32x2*)(outp + ((size_t)((bb * NH + hh) * S_LEN + s)) * HD + d0) = ov;
            }
        }
    }
}

// ---------------------------------------------------------------------------
// Flash attention (R9/R13-measured structure). 256-thread blocks = 4 waves x
// 16 q-rows (64 rows/block). Grid 1024: id = qbr*32 + g, g=(b,h) low 5 bits
// -> XCD pin; qb = 31-qbr (longest-first). Counted-vmcnt K dbuf + V single;
// swizzled LDS; cvt_pk epilogue; defer-max (T13, THR=8).
// ---------------------------------------------------------------------------
__global__ __launch_bounds__(256, 4) void attn_kernel(
    const u16* __restrict__ qws, const u16* __restrict__ kws,
    const u16* __restrict__ vT, u16* __restrict__ ows) {
    __shared__ __align__(16) u16 kl[2][64 * 64];    // K dbuf, 16 KB
    __shared__ __align__(16) u16 vl[64 * 64];       // V single, 8 KB
    __shared__ __align__(16) u32 pl32[4][16 * 36];  // per-wave P, 9216 B
    const int t = threadIdx.x;
    const int w = __builtin_amdgcn_readfirstlane(t >> 6);
    const int lane = t & 63;
    const int quad = lane >> 4;
    const int l16 = lane & 15;

    const int id = blockIdx.x;
    const int g = id & 31;          // (b,h) -> XCD pin g%8
    const int qb = 31 - (id >> 5);  // longest-first
    const int h = g & 15, b = g >> 4;
    const int q0 = qb * 64 + w * 16;  // wave's 16 q-rows

    const size_t bh = (size_t)(b * NH + h);
    const u16* qbp = qws + bh * (size_t)S_LEN * HD;
    const u16* kb = kws + bh * (size_t)S_LEN * HD;
    const u16* vb = vT + bh * (size_t)HD * S_LEN;

    // staging geometry: wave w stages rows [w*8+s*32 .. +7], lane -> 16B
    const int r0 = lane >> 3;                // row within 8-row group
    const int srcc = (lane & 7) ^ r0;        // pre-swizzled col16
    const int xorb = (l16 & 7) << 4;         // read-side swizzle XOR

    short8v qf[2];
#pragma unroll
    for (int hf = 0; hf < 2; ++hf)
        qf[hf] = *(const short8v*)(qbp + (size_t)(q0 + l16) * HD + hf * 32 + quad * 8);

    f32x4 oaccT[4];  // row = d (quad*4+r), col = q (l16)
#pragma unroll
    for (int d = 0; d < 4; ++d) oaccT[d] = {0.f, 0.f, 0.f, 0.f};
    float mrow = -__builtin_inff();
    float lrow = 0.f;

    // prologue: stage K[0]
#pragma unroll
    for (int s = 0; s < 2; ++s) {
        const int row = w * 8 + s * 32 + r0;
        gld_lds16(kb + (size_t)row * HD + srcc * 8, (char*)&kl[0][0] + w * 1024 + s * 4096);
    }

    int cur = 0;
    for (int kt = 0; kt <= qb; ++kt) {
        __syncthreads();  // K[kt] staged by all; V free; kl[cur^1] free
        // issue V[kt] FIRST (oldest in vm queue), then K[kt+1]
#pragma unroll
        for (int s = 0; s < 2; ++s) {
            const int row = w * 8 + s * 32 + r0;
            gld_lds16(vb + (size_t)row * S_LEN + kt * 64 + srcc * 8,
                      (char*)&vl[0] + w * 1024 + s * 4096);
        }
        if (kt < qb) {
#pragma unroll
            for (int s = 0; s < 2; ++s) {
                const int row = w * 8 + s * 32 + r0;
                gld_lds16(kb + (size_t)((kt + 1) * 64 + row) * HD + srcc * 8,
                          (char*)&kl[cur ^ 1][0] + w * 1024 + s * 4096);
            }
        }
        const char* Kb = (const char*)&kl[cur][0];

        // S^T sub-tiles: row = k (quad*4+r within sub), col = q (l16)
        f32x4 s4[4];
        __builtin_amdgcn_s_setprio(1);
#pragma unroll
        for (int sub = 0; sub < 4; ++sub) {
            const int lin = (sub * 16 + l16) * 128 + quad * 16;
            const short8v k0 = *(const short8v*)(Kb + (lin ^ xorb));
            const short8v k1 = *(const short8v*)(Kb + ((lin + 64) ^ xorb));
            f32x4 a = {0.f, 0.f, 0.f, 0.f};
            a = __builtin_amdgcn_mfma_f32_16x16x32_bf16(k0, qf[0], a, 0, 0, 0);
            a = __builtin_amdgcn_mfma_f32_16x16x32_bf16(k1, qf[1], a, 0, 0, 0);
            s4[sub] = a;
        }
        __builtin_amdgcn_s_setprio(0);
        float sv[16];
#pragma unroll
        for (int sub = 0; sub < 4; ++sub)
#pragma unroll
            for (int r = 0; r < 4; ++r) sv[sub * 4 + r] = s4[sub][r] * 0.125f;
        if (kt == qb) {  // masked diagonal tile: k > q -> -inf
            const int qloc = w * 16 + l16;
#pragma unroll
            for (int sub = 0; sub < 4; ++sub)
#pragma unroll
                for (int r = 0; r < 4; ++r)
                    if (sub * 16 + quad * 4 + r > qloc) sv[sub * 4 + r] = -__builtin_inff();
        }
        // per-q-row max: 15 in-lane (tree) + 2 cross-lane
        float a0 = fmaxf(sv[0], sv[1]), a1 = fmaxf(sv[2], sv[3]);
        float a2 = fmaxf(sv[4], sv[5]), a3 = fmaxf(sv[6], sv[7]);
        float a4 = fmaxf(sv[8], sv[9]), a5 = fmaxf(sv[10], sv[11]);
        float a6 = fmaxf(sv[12], sv[13]), a7 = fmaxf(sv[14], sv[15]);
        a0 = fmaxf(a0, a1); a2 = fmaxf(a2, a3);
        a4 = fmaxf(a4, a5); a6 = fmaxf(a6, a7);
        a0 = fmaxf(a0, a2); a4 = fmaxf(a4, a6);
        float mx = fmaxf(a0, a4);
        mx = fmaxf(mx, __shfl_xor(mx, 16));
        mx = fmaxf(mx, __shfl_xor(mx, 32));
        // defer-max (T13): rescale only when some row's max grew by > 8
        if (!__all(mx - mrow <= 8.0f)) {
            const float mnew = fmaxf(mrow, mx);
            const float alpha = __expf(mrow - mnew);
            mrow = mnew;
            lrow *= alpha;
#pragma unroll
            for (int d = 0; d < 4; ++d) oaccT[d] *= alpha;
        }
        float p[16];
#pragma unroll
        for (int i = 0; i < 16; ++i) p[i] = __expf(sv[i] - mrow);
        float b0 = p[0] + p[1], b1 = p[2] + p[3], b2 = p[4] + p[5], b3 = p[6] + p[7];
        float b4 = p[8] + p[9], b5 = p[10] + p[11], b6 = p[12] + p[13], b7 = p[14] + p[15];
        b0 += b1; b2 += b3; b4 += b5; b6 += b7;
        b0 += b2; b4 += b6;
        float ps = b0 + b4;
        ps += __shfl_xor(ps, 16);
        ps += __shfl_xor(ps, 32);
        lrow += ps;
        // pack P[q=l16][k] via cvt_pk; 4x b64 writes (stride-36 rows)
        u32* prow = &pl32[w][l16 * 36];
#pragma unroll
        for (int sub = 0; sub < 4; ++sub) {
            u32x2 pw;
            pw.x = cvtpk(p[sub * 4 + 0], p[sub * 4 + 1]);
            pw.y = cvtpk(p[sub * 4 + 2], p[sub * 4 + 3]);
            *(u32x2*)&prow[sub * 8 + quad * 2] = pw;
        }
        asm volatile("s_waitcnt lgkmcnt(0)" ::: "memory");  // P visible (DS in-order)
        // wait own V chunks (K[kt+1] stays in flight), then join
        if (kt < qb) {
            asm volatile("s_waitcnt vmcnt(2)" ::: "memory");
        } else {
            asm volatile("s_waitcnt vmcnt(0)" ::: "memory");
        }
        __builtin_amdgcn_s_barrier();
        asm volatile("" ::: "memory");
        // PV: B-frag = P[q][c2*32 + quad*8 .. +7]; A-frag = V^T rows
        __builtin_amdgcn_s_setprio(1);
#pragma unroll
        for (int c2 = 0; c2 < 2; ++c2) {
            const short8v pf = *(const short8v*)&pl32[w][l16 * 36 + c2 * 16 + quad * 4];
#pragma unroll
            for (int d = 0; d < 4; ++d) {
                const int lin = (d * 16 + l16) * 128 + c2 * 64 + quad * 16;
                const short8v vfd = *(const short8v*)((const char*)&vl[0] + (lin ^ xorb));
                oaccT[d] = __builtin_amdgcn_mfma_f32_16x16x32_bf16(vfd, pf, oaccT[d], 0, 0, 0);
            }
        }
        __builtin_amdgcn_s_setprio(0);
        cur ^= 1;
    }

    // epilogue: O[q][d], q = q0+l16, d = df*16+quad*4+r -> 8B packed stores
    const float inv = 1.0f / lrow;
    const size_t rowbase = ((size_t)(b * S_LEN + q0 + l16)) * DM + h * HD;
#pragma unroll
    for (int df = 0; df < 4; ++df) {
        const int d0 = df * 16 + quad * 4;
        u32x2 ov;
        ov.x = cvtpk(oaccT[df][0] * inv, oaccT[df][1] * inv);
        ov.y = cvtpk(oaccT[df][2] * inv, oaccT[df][3] * inv);
        *(u32x2*)(ows + rowbase + d0) = ov;
    }
}

extern "C" void kernel_launch(void* const* d_in, const int* in_sizes, int n_in,
                              void* d_out, int out_size, void* d_ws, size_t ws_size,
                              hipStream_t stream) {
    const void* x = d_in[0];
    const void* w_qkv = d_in[1];
    const void* b_qkv = d_in[2];
    const void* w_out = d_in[3];
    const void* b_out = d_in[4];

    int* flag = (int*)d_ws;
    u16* xb = (u16*)d_ws + 8;                        // 8 MB
    u16* wqkvb = xb + (size_t)TOK * DM;              // 6 MB
    u16* woutb = wqkvb + (size_t)3 * DM * DM;        // 2 MB
    u16* qws = woutb + (size_t)DM * DM;              // (B,H,S,64) 8 MB
    u16* kws = qws + (size_t)NB * NH * S_LEN * HD;   // 8 MB
    u16* vT = kws + (size_t)NB * NH * S_LEN * HD;    // (B,H,64,S) 8 MB
    u16* ows = vT + (size_t)NB * NH * HD * S_LEN;    // attn out (B,S,DM) 8 MB
    float* tab = (float*)(ows + (size_t)TOK * DM);   // 16x2048 f32x4 = 512 KB

    detect_dtype<<<1, 256, 0, stream>>>((const u32*)x, flag);
    convert_all<<<(CONVTOT + TABN) / 256, 256, 0, stream>>>(
        x, w_qkv, w_out, xb, wqkvb, woutb, tab, flag);

    // fused QKV GEMM: q/k (RoPE) and v (transpose) instantiations, 1-D grids
    // with XCD rectangle swizzle
    gemm_k<1><<<dim3(512), 256, 0, stream>>>(
        xb, wqkvb, b_qkv, nullptr, TOK, 3 * DM, DM, flag, 0, qws, kws, nullptr, tab);
    gemm_k<2><<<dim3(256), 256, 0, stream>>>(
        xb, wqkvb, b_qkv, nullptr, TOK, 3 * DM, DM, flag, 0, nullptr, nullptr, vT, nullptr);
    // 1-D grid: id = qbr*32 + g, g=(b,h). 1024 blocks x 256 threads.
    attn_kernel<<<dim3(32 * 32), 256, 0, stream>>>(qws, kws, vT, ows);
    gemm_k<0><<<dim3(256), 256, 0, stream>>>(
        ows, woutb, b_out, d_out, TOK, DM, DM, flag, 1, nullptr, nullptr, nullptr, nullptr);
}